// Round 12
// baseline (59.550 us; speedup 1.0000x reference)
//
#include <hip/hip_runtime.h>
#include <math.h>

#define BATCH 512
#define HH 224
#define WW 224
#define NPIX (HH * WW)
#define NL 3
#define EPSV 1e-5f
#define GROUPS 14            // row-groups (blocks) per image; block covers 16 rows
#define ROWS_PER_WAVE 4      // wave covers 4 output rows; 6 input rows

// ---------------- Kernel 1: conv3x3(1->4) + relu + partial sums ----------------
// Grid: 512 images * 14 groups. Block: 256 threads = 4 waves; wave owns 4 output
// rows; lane owns 4 cols. NO cross-lane ops in the hot path (R11 diagnosis: the
// per-row __shfl expand forced vmcnt->ds_bpermute->lgkmcnt->FMA serial chains,
// pinning VALUBusy at ~50% across R6-R11). Each lane loads its full 6-col window
// per input row directly: one aligned float4 (cols 4l..4l+3) + two scalar dwords
// (cols 4l-1, 4l+4). 18 independent VMEM ops up-front, then pure FMA.
// Edges: lane0 left dword := 0 (col -1), lane55 right dword := 0 (col 224),
// lanes 56..63 clamp addresses to lane55 and zero accs pre-reduce (R2 lesson),
// OOB rows clamped then zeroed wave-uniformly. R5: no min-waves clause.
__global__ __launch_bounds__(256) void conv_pool_k(
    const float* __restrict__ x, const float* __restrict__ cw,
    float* __restrict__ part)
{
  const int blk = blockIdx.x;
  const int b = blk / GROUPS;      // image
  const int g = blk % GROUPS;      // row-group
  const int tid = threadIdx.x;
  const int wv = __builtin_amdgcn_readfirstlane(tid >> 6);  // SGPR wave id
  const int lane = tid & 63;
  const int r0 = g * 16 + wv * ROWS_PER_WAVE;   // first output row (SGPR)
  const int le = lane < 56 ? lane : 55;         // clamped lane
  const int cm = le * 4;                        // main quad col
  const int cl = (le == 0) ? 0 : cm - 1;        // left scalar col (garbage if le==0)
  const int cr = (le == 55) ? 216 : cm + 4;     // right scalar col (garbage if le==55)
  const float* __restrict__ img = x + (size_t)b * NPIX;

  // 4x9 weights: uniform address -> scalar loads -> SGPRs
  float K[4][9];
#pragma unroll
  for (int o = 0; o < 4; ++o)
#pragma unroll
    for (int k = 0; k < 9; ++k) K[o][k] = cw[o * 9 + k];

  // ---- load all 6 input rows up front: per row 1 float4 + 2 dwords ----
  float4 vM[6];
  float  wL[6], wR[6];
#pragma unroll
  for (int k = 0; k < 6; ++k) {
    int rr = r0 - 1 + k;                        // wave-uniform
    int rc = rr < 0 ? 0 : (rr > HH - 1 ? HH - 1 : rr);
    const float* base = img + (size_t)rc * WW;
    vM[k] = *reinterpret_cast<const float4*>(base + cm);
    wL[k] = base[cl];
    wR[k] = base[cr];
  }
  // zero logically-OOB rows (wave-uniform; only first/last group hit)
#pragma unroll
  for (int k = 0; k < 6; ++k) {
    int rr = r0 - 1 + k;
    if (rr < 0 || rr > HH - 1) {
      vM[k] = make_float4(0.f, 0.f, 0.f, 0.f);
      wL[k] = 0.f; wR[k] = 0.f;
    }
  }
  // image left/right edges (one-time, not per-pixel)
  if (lane == 0) {
#pragma unroll
    for (int k = 0; k < 6; ++k) wL[k] = 0.f;
  }
  if (lane == 55) {
#pragma unroll
    for (int k = 0; k < 6; ++k) wR[k] = 0.f;
  }
  // pin the load batch (per-scalar ties; R10: float4 ties don't lower)
#pragma unroll
  for (int k = 0; k < 6; ++k)
    asm volatile("" : "+v"(vM[k].x), "+v"(vM[k].y), "+v"(vM[k].z), "+v"(vM[k].w),
                      "+v"(wL[k]), "+v"(wR[k]));
  __builtin_amdgcn_sched_barrier(0);

  float acc0 = 0.f, acc1 = 0.f, acc2 = 0.f, acc3 = 0.f;

#pragma unroll
  for (int i = 0; i < ROWS_PER_WAVE; ++i) {   // 4 output rows
    const float A[6] = { wL[i],     vM[i].x,     vM[i].y,     vM[i].z,     vM[i].w,     wR[i] };
    const float B[6] = { wL[i + 1], vM[i + 1].x, vM[i + 1].y, vM[i + 1].z, vM[i + 1].w, wR[i + 1] };
    const float C[6] = { wL[i + 2], vM[i + 2].x, vM[i + 2].y, vM[i + 2].z, vM[i + 2].w, wR[i + 2] };

#pragma unroll
    for (int p = 0; p < 4; ++p) {
      const float a0 = A[p], a1 = A[p + 1], a2 = A[p + 2];
      const float b0 = B[p], b1 = B[p + 1], b2 = B[p + 2];
      const float c0 = C[p], c1 = C[p + 1], c2 = C[p + 2];
      float t0 = fmaf(a0, K[0][0], fmaf(a1, K[0][1], fmaf(a2, K[0][2],
                 fmaf(b0, K[0][3], fmaf(b1, K[0][4], fmaf(b2, K[0][5],
                 fmaf(c0, K[0][6], fmaf(c1, K[0][7], c2 * K[0][8]))))))));
      float t1 = fmaf(a0, K[1][0], fmaf(a1, K[1][1], fmaf(a2, K[1][2],
                 fmaf(b0, K[1][3], fmaf(b1, K[1][4], fmaf(b2, K[1][5],
                 fmaf(c0, K[1][6], fmaf(c1, K[1][7], c2 * K[1][8]))))))));
      float t2 = fmaf(a0, K[2][0], fmaf(a1, K[2][1], fmaf(a2, K[2][2],
                 fmaf(b0, K[2][3], fmaf(b1, K[2][4], fmaf(b2, K[2][5],
                 fmaf(c0, K[2][6], fmaf(c1, K[2][7], c2 * K[2][8]))))))));
      float t3 = fmaf(a0, K[3][0], fmaf(a1, K[3][1], fmaf(a2, K[3][2],
                 fmaf(b0, K[3][3], fmaf(b1, K[3][4], fmaf(b2, K[3][5],
                 fmaf(c0, K[3][6], fmaf(c1, K[3][7], c2 * K[3][8]))))))));
      acc0 += fmaxf(t0, 0.f);
      acc1 += fmaxf(t1, 0.f);
      acc2 += fmaxf(t2, 0.f);
      acc3 += fmaxf(t3, 0.f);
    }
  }

  // lanes 56..63 computed lane55's duplicate columns: zero before reduction
  if (lane >= 56) { acc0 = 0.f; acc1 = 0.f; acc2 = 0.f; acc3 = 0.f; }

  // wave reduce, cross-wave via LDS, one partial per block
#pragma unroll
  for (int off = 32; off > 0; off >>= 1) {
    acc0 += __shfl_down(acc0, off);
    acc1 += __shfl_down(acc1, off);
    acc2 += __shfl_down(acc2, off);
    acc3 += __shfl_down(acc3, off);
  }
  __shared__ float pl[4][4];
  if (lane == 0) {
    pl[wv][0] = acc0; pl[wv][1] = acc1; pl[wv][2] = acc2; pl[wv][3] = acc3;
  }
  __syncthreads();
  if (tid < 4) {
    float ssum = 0.f;
#pragma unroll
    for (int w = 0; w < 4; ++w) ssum += pl[w][tid];
    part[blk * 4 + tid] = ssum;
  }
}

// ---------------- Kernel 2: 4-qubit circuit + BatchNorm ----------------
template <int M>
__device__ __forceinline__ void ry_g(float (&sr)[16], float (&si)[16], float th) {
  float s, c;
  sincosf(0.5f * th, &s, &c);
#pragma unroll
  for (int i = 0; i < 16; ++i) {
    if (!(i & M)) {
      const int j = i | M;
      float r0 = sr[i], q0 = si[i], r1 = sr[j], q1 = si[j];
      sr[i] = c * r0 - s * r1;  si[i] = c * q0 - s * q1;
      sr[j] = s * r0 + c * r1;  si[j] = s * q0 + c * q1;
    }
  }
}

template <int M>
__device__ __forceinline__ void rz_g(float (&sr)[16], float (&si)[16], float th) {
  float s, c;
  sincosf(0.5f * th, &s, &c);
#pragma unroll
  for (int i = 0; i < 16; ++i) {
    float a = sr[i], q = si[i];
    if (i & M) { sr[i] = a * c - q * s;  si[i] = q * c + a * s; }
    else       { sr[i] = a * c + q * s;  si[i] = q * c - a * s; }
  }
}

template <int MC, int MT>
__device__ __forceinline__ void cnot_g(float (&sr)[16], float (&si)[16]) {
#pragma unroll
  for (int i = 0; i < 16; ++i) {
    if ((i & MC) && !(i & MT)) {
      const int j = i | MT;
      float tr = sr[i]; sr[i] = sr[j]; sr[j] = tr;
      float ti = si[i]; si[i] = si[j]; si[j] = ti;
    }
  }
}

__global__ __launch_bounds__(512) void circuit_bn_k(
    const float* __restrict__ part, const float* __restrict__ params,
    const float* __restrict__ gamma, const float* __restrict__ beta,
    float* __restrict__ out)
{
  const int b = threadIdx.x;  // batch element

  // gather 14 group partials per channel (float4 per group) -> features
  float4 fs = make_float4(0.f, 0.f, 0.f, 0.f);
#pragma unroll
  for (int s8 = 0; s8 < GROUPS; ++s8) {
    const float4 q = *reinterpret_cast<const float4*>(&part[(b * GROUPS + s8) * 4]);
    fs.x += q.x; fs.y += q.y; fs.z += q.z; fs.w += q.w;
  }
  float f[4] = { fs.x * (1.0f / NPIX), fs.y * (1.0f / NPIX),
                 fs.z * (1.0f / NPIX), fs.w * (1.0f / NPIX) };

  float sr[16], si[16];
#pragma unroll
  for (int i = 0; i < 16; ++i) { sr[i] = 0.f; si[i] = 0.f; }
  sr[0] = 1.f;

  ry_g<8>(sr, si, f[0]);
  ry_g<4>(sr, si, f[1]);
  ry_g<2>(sr, si, f[2]);
  ry_g<1>(sr, si, f[3]);

  for (int l = 0; l < NL; ++l) {
    const float* pp = params + l * 8;
    ry_g<8>(sr, si, pp[0]); rz_g<8>(sr, si, pp[1]);
    ry_g<4>(sr, si, pp[2]); rz_g<4>(sr, si, pp[3]);
    ry_g<2>(sr, si, pp[4]); rz_g<2>(sr, si, pp[5]);
    ry_g<1>(sr, si, pp[6]); rz_g<1>(sr, si, pp[7]);
    cnot_g<8, 4>(sr, si);
    cnot_g<4, 2>(sr, si);
    cnot_g<2, 1>(sr, si);
  }

  float p[16];
#pragma unroll
  for (int i = 0; i < 16; ++i) p[i] = sr[i] * sr[i] + si[i] * si[i];

  float ev[4];
#pragma unroll
  for (int w = 0; w < 4; ++w) {
    const int m = 8 >> w;
    float ssum = 0.f;
#pragma unroll
    for (int i = 0; i < 16; ++i) ssum += (i & m) ? -p[i] : p[i];
    ev[w] = ssum;
  }

  // BatchNorm over batch of 512 (biased variance) within this single block
  float sum[4], sq[4];
#pragma unroll
  for (int w = 0; w < 4; ++w) { sum[w] = ev[w]; sq[w] = ev[w] * ev[w]; }
#pragma unroll
  for (int off = 32; off > 0; off >>= 1) {
#pragma unroll
    for (int w = 0; w < 4; ++w) {
      sum[w] += __shfl_down(sum[w], off);
      sq[w]  += __shfl_down(sq[w],  off);
    }
  }
  __shared__ float psum[8][4], psq[8][4];
  __shared__ float mean_s[4], rstd_s[4];
  const int wave = b >> 6;
  const int lane = b & 63;
  if (lane == 0) {
#pragma unroll
    for (int w = 0; w < 4; ++w) { psum[wave][w] = sum[w]; psq[wave][w] = sq[w]; }
  }
  __syncthreads();
  if (b < 4) {
    float ssum = 0.f, q = 0.f;
#pragma unroll
    for (int wv = 0; wv < 8; ++wv) { ssum += psum[wv][b]; q += psq[wv][b]; }
    const float m = ssum * (1.0f / BATCH);
    const float v = q * (1.0f / BATCH) - m * m;
    mean_s[b] = m;
    rstd_s[b] = rsqrtf(v + EPSV);
  }
  __syncthreads();
#pragma unroll
  for (int w = 0; w < 4; ++w) {
    out[b * 4 + w] = gamma[w] * (ev[w] - mean_s[w]) * rstd_s[w] + beta[w];
  }
}

extern "C" void kernel_launch(void* const* d_in, const int* in_sizes, int n_in,
                              void* d_out, int out_size, void* d_ws, size_t ws_size,
                              hipStream_t stream) {
  const float* x      = (const float*)d_in[0];
  const float* cw     = (const float*)d_in[1];
  const float* params = (const float*)d_in[2];
  const float* gamma  = (const float*)d_in[3];
  const float* beta   = (const float*)d_in[4];
  float* out  = (float*)d_out;
  float* part = (float*)d_ws;   // 512*14*4 f32 partial sums (~114 KB)

  const int B = in_sizes[0] / NPIX;  // 512

  conv_pool_k<<<B * GROUPS, 256, 0, stream>>>(x, cw, part);
  circuit_bn_k<<<1, 512, 0, stream>>>(part, params, gamma, beta, out);
}

// Round 13
// 52.384 us; speedup vs baseline: 1.1368x; 1.1368x over previous
//
#include <hip/hip_runtime.h>
#include <math.h>

#define BATCH 512
#define HH 224
#define WW 224
#define NPIX (HH * WW)
#define NL 3
#define EPSV 1e-5f
#define GROUPS 8             // strips per image (one per WAVE)

// ---------------- Kernel 1: conv3x3(1->4) + relu + partial sums ----------------
// Persistent per-wave pipeline. One wave owns a 28-row strip (4096 waves, 1024
// blocks, all resident). 7 groups of 4 output rows; per iteration:
//   [issue next 4 row loads] sched_barrier(0) [compute from resident rv]
//   sched_barrier(0) [vmcnt wait lands HERE at first nv use -> roll]
// -> every wave has loads in flight WHILE computing (R12 diagnosis: all prior
// variants serialized global load-phase and compute-phase; ~16us HBM + ~30us
// VALU added instead of overlapped).
// Lessons kept: R2 zero clamped lanes pre-reduce; R4 direct indexing; R5 no
// min-waves clause; R6/R9 loads sink unless fenced -> sched_barrier regions;
// R12 shfl expand beats 3x VMEM/row.
__global__ __launch_bounds__(256) void conv_pool_k(
    const float* __restrict__ x, const float* __restrict__ cw,
    float* __restrict__ part)
{
  const int tid = threadIdx.x;
  const int wv = tid >> 6;
  const int lane = tid & 63;
  const int W = blockIdx.x * 4 + wv;   // global wave id
  const int b = W >> 3;                // image
  const int s = W & 7;                 // strip
  const int base = s * 28;             // first output row of strip
  const int colc = (lane < 56 ? lane : 55) * 4;  // clamped col
  const float* __restrict__ img = x + (size_t)b * NPIX;

  // 4x9 weights: uniform address -> scalar loads -> SGPRs
  float K[4][9];
#pragma unroll
  for (int o = 0; o < 4; ++o)
#pragma unroll
    for (int k = 0; k < 9; ++k) K[o][k] = cw[o * 9 + k];

  // clamped row load (address always valid; logical OOB zeroed separately)
  auto ldrow = [&](int ar) -> float4 {
    int rc = ar < 0 ? 0 : (ar > HH - 1 ? HH - 1 : ar);
    return *reinterpret_cast<const float4*>(img + (size_t)rc * WW + colc);
  };
  // expand float4 into [left, x, y, z, w, right] via cross-lane shfl
  auto expand = [&](const float4& t, float (&R)[6]) {
    float lft = __shfl_up(t.w, 1);
    R[0] = (lane == 0) ? 0.f : lft;     // image left edge
    float rgt = __shfl_down(t.x, 1);
    R[5] = (lane == 55) ? 0.f : rgt;    // image right edge (lane56 dups lane55)
    R[1] = t.x; R[2] = t.y; R[3] = t.z; R[4] = t.w;
  };

  // prologue: window rows base-1 .. base+4  (rv[k] = abs row base-1+k)
  float4 rv[6];
#pragma unroll
  for (int k = 0; k < 6; ++k) rv[k] = ldrow(base - 1 + k);
  if (s == 0) rv[0] = make_float4(0.f, 0.f, 0.f, 0.f);  // row -1

  float acc0 = 0.f, acc1 = 0.f, acc2 = 0.f, acc3 = 0.f;

#pragma unroll
  for (int j = 0; j < 7; ++j) {        // 7 groups of 4 output rows
    // ---- issue next group's loads (rows base+4j+5 .. +8) ----
    float4 nv[4];
    if (j < 6) {
#pragma unroll
      for (int k = 0; k < 4; ++k) nv[k] = ldrow(base + 4 * j + 5 + k);
    }
    __builtin_amdgcn_sched_barrier(0);  // loads may not sink into compute

    // ---- compute group j from resident rv[0..5] ----
    float E[3][6];
    expand(rv[0], E[0]);
    expand(rv[1], E[1]);
#pragma unroll
    for (int i = 0; i < 4; ++i) {      // output row base+4j+i
      expand(rv[i + 2], E[(i + 2) % 3]);
      float (&A)[6] = E[i % 3];
      float (&B)[6] = E[(i + 1) % 3];
      float (&C)[6] = E[(i + 2) % 3];
#pragma unroll
      for (int p = 0; p < 4; ++p) {
        const float a0 = A[p], a1 = A[p + 1], a2 = A[p + 2];
        const float b0 = B[p], b1 = B[p + 1], b2 = B[p + 2];
        const float c0 = C[p], c1 = C[p + 1], c2 = C[p + 2];
        float t0 = fmaf(a0, K[0][0], fmaf(a1, K[0][1], fmaf(a2, K[0][2],
                   fmaf(b0, K[0][3], fmaf(b1, K[0][4], fmaf(b2, K[0][5],
                   fmaf(c0, K[0][6], fmaf(c1, K[0][7], c2 * K[0][8]))))))));
        float t1 = fmaf(a0, K[1][0], fmaf(a1, K[1][1], fmaf(a2, K[1][2],
                   fmaf(b0, K[1][3], fmaf(b1, K[1][4], fmaf(b2, K[1][5],
                   fmaf(c0, K[1][6], fmaf(c1, K[1][7], c2 * K[1][8]))))))));
        float t2 = fmaf(a0, K[2][0], fmaf(a1, K[2][1], fmaf(a2, K[2][2],
                   fmaf(b0, K[2][3], fmaf(b1, K[2][4], fmaf(b2, K[2][5],
                   fmaf(c0, K[2][6], fmaf(c1, K[2][7], c2 * K[2][8]))))))));
        float t3 = fmaf(a0, K[3][0], fmaf(a1, K[3][1], fmaf(a2, K[3][2],
                   fmaf(b0, K[3][3], fmaf(b1, K[3][4], fmaf(b2, K[3][5],
                   fmaf(c0, K[3][6], fmaf(c1, K[3][7], c2 * K[3][8]))))))));
        acc0 += fmaxf(t0, 0.f);
        acc1 += fmaxf(t1, 0.f);
        acc2 += fmaxf(t2, 0.f);
        acc3 += fmaxf(t3, 0.f);
      }
    }
    __builtin_amdgcn_sched_barrier(0);  // compute may not sink below roll

    // ---- roll window; first nv use -> vmcnt wait lands here (after compute) ----
    if (j < 6) {
      rv[0] = rv[4]; rv[1] = rv[5];
      rv[2] = nv[0]; rv[3] = nv[1]; rv[4] = nv[2]; rv[5] = nv[3];
      if (j == 5 && s == 7) rv[5] = make_float4(0.f, 0.f, 0.f, 0.f);  // row 224
    }
  }

  // lanes 56..63 computed lane55's duplicate columns: zero before reduction
  if (lane >= 56) { acc0 = 0.f; acc1 = 0.f; acc2 = 0.f; acc3 = 0.f; }

  // wave-level reduce; one partial per WAVE (no LDS, no barrier)
#pragma unroll
  for (int off = 32; off > 0; off >>= 1) {
    acc0 += __shfl_down(acc0, off);
    acc1 += __shfl_down(acc1, off);
    acc2 += __shfl_down(acc2, off);
    acc3 += __shfl_down(acc3, off);
  }
  if (lane == 0) {
    *reinterpret_cast<float4*>(part + (size_t)W * 4) =
        make_float4(acc0, acc1, acc2, acc3);
  }
}

// ---------------- Kernel 2: 4-qubit circuit + BatchNorm ----------------
template <int M>
__device__ __forceinline__ void ry_g(float (&sr)[16], float (&si)[16], float th) {
  float s, c;
  sincosf(0.5f * th, &s, &c);
#pragma unroll
  for (int i = 0; i < 16; ++i) {
    if (!(i & M)) {
      const int j = i | M;
      float r0 = sr[i], q0 = si[i], r1 = sr[j], q1 = si[j];
      sr[i] = c * r0 - s * r1;  si[i] = c * q0 - s * q1;
      sr[j] = s * r0 + c * r1;  si[j] = s * q0 + c * q1;
    }
  }
}

template <int M>
__device__ __forceinline__ void rz_g(float (&sr)[16], float (&si)[16], float th) {
  float s, c;
  sincosf(0.5f * th, &s, &c);
#pragma unroll
  for (int i = 0; i < 16; ++i) {
    float a = sr[i], q = si[i];
    if (i & M) { sr[i] = a * c - q * s;  si[i] = q * c + a * s; }
    else       { sr[i] = a * c + q * s;  si[i] = q * c - a * s; }
  }
}

template <int MC, int MT>
__device__ __forceinline__ void cnot_g(float (&sr)[16], float (&si)[16]) {
#pragma unroll
  for (int i = 0; i < 16; ++i) {
    if ((i & MC) && !(i & MT)) {
      const int j = i | MT;
      float tr = sr[i]; sr[i] = sr[j]; sr[j] = tr;
      float ti = si[i]; si[i] = si[j]; si[j] = ti;
    }
  }
}

__global__ __launch_bounds__(512) void circuit_bn_k(
    const float* __restrict__ part, const float* __restrict__ params,
    const float* __restrict__ gamma, const float* __restrict__ beta,
    float* __restrict__ out)
{
  const int b = threadIdx.x;  // batch element

  // gather 8 strip partials per channel -> features
  float4 fs = make_float4(0.f, 0.f, 0.f, 0.f);
#pragma unroll
  for (int s8 = 0; s8 < GROUPS; ++s8) {
    const float4 q = *reinterpret_cast<const float4*>(&part[(b * GROUPS + s8) * 4]);
    fs.x += q.x; fs.y += q.y; fs.z += q.z; fs.w += q.w;
  }
  float f[4] = { fs.x * (1.0f / NPIX), fs.y * (1.0f / NPIX),
                 fs.z * (1.0f / NPIX), fs.w * (1.0f / NPIX) };

  float sr[16], si[16];
#pragma unroll
  for (int i = 0; i < 16; ++i) { sr[i] = 0.f; si[i] = 0.f; }
  sr[0] = 1.f;

  ry_g<8>(sr, si, f[0]);
  ry_g<4>(sr, si, f[1]);
  ry_g<2>(sr, si, f[2]);
  ry_g<1>(sr, si, f[3]);

  for (int l = 0; l < NL; ++l) {
    const float* pp = params + l * 8;
    ry_g<8>(sr, si, pp[0]); rz_g<8>(sr, si, pp[1]);
    ry_g<4>(sr, si, pp[2]); rz_g<4>(sr, si, pp[3]);
    ry_g<2>(sr, si, pp[4]); rz_g<2>(sr, si, pp[5]);
    ry_g<1>(sr, si, pp[6]); rz_g<1>(sr, si, pp[7]);
    cnot_g<8, 4>(sr, si);
    cnot_g<4, 2>(sr, si);
    cnot_g<2, 1>(sr, si);
  }

  float p[16];
#pragma unroll
  for (int i = 0; i < 16; ++i) p[i] = sr[i] * sr[i] + si[i] * si[i];

  float ev[4];
#pragma unroll
  for (int w = 0; w < 4; ++w) {
    const int m = 8 >> w;
    float ssum = 0.f;
#pragma unroll
    for (int i = 0; i < 16; ++i) ssum += (i & m) ? -p[i] : p[i];
    ev[w] = ssum;
  }

  // BatchNorm over batch of 512 (biased variance) within this single block
  float sum[4], sq[4];
#pragma unroll
  for (int w = 0; w < 4; ++w) { sum[w] = ev[w]; sq[w] = ev[w] * ev[w]; }
#pragma unroll
  for (int off = 32; off > 0; off >>= 1) {
#pragma unroll
    for (int w = 0; w < 4; ++w) {
      sum[w] += __shfl_down(sum[w], off);
      sq[w]  += __shfl_down(sq[w],  off);
    }
  }
  __shared__ float psum[8][4], psq[8][4];
  __shared__ float mean_s[4], rstd_s[4];
  const int wave = b >> 6;
  const int lane = b & 63;
  if (lane == 0) {
#pragma unroll
    for (int w = 0; w < 4; ++w) { psum[wave][w] = sum[w]; psq[wave][w] = sq[w]; }
  }
  __syncthreads();
  if (b < 4) {
    float ssum = 0.f, q = 0.f;
#pragma unroll
    for (int wv = 0; wv < 8; ++wv) { ssum += psum[wv][b]; q += psq[wv][b]; }
    const float m = ssum * (1.0f / BATCH);
    const float v = q * (1.0f / BATCH) - m * m;
    mean_s[b] = m;
    rstd_s[b] = rsqrtf(v + EPSV);
  }
  __syncthreads();
#pragma unroll
  for (int w = 0; w < 4; ++w) {
    out[b * 4 + w] = gamma[w] * (ev[w] - mean_s[w]) * rstd_s[w] + beta[w];
  }
}

extern "C" void kernel_launch(void* const* d_in, const int* in_sizes, int n_in,
                              void* d_out, int out_size, void* d_ws, size_t ws_size,
                              hipStream_t stream) {
  const float* x      = (const float*)d_in[0];
  const float* cw     = (const float*)d_in[1];
  const float* params = (const float*)d_in[2];
  const float* gamma  = (const float*)d_in[3];
  const float* beta   = (const float*)d_in[4];
  float* out  = (float*)d_out;
  float* part = (float*)d_ws;   // 4096 waves * 4 f32 partials (64 KB)

  const int B = in_sizes[0] / NPIX;  // 512

  conv_pool_k<<<B * GROUPS / 4, 256, 0, stream>>>(x, cw, part);
  circuit_bn_k<<<1, 512, 0, stream>>>(part, params, gamma, beta, out);
}